// Round 1
// baseline (293.324 us; speedup 1.0000x reference)
//
#include <hip/hip_runtime.h>
#include <hip/hip_bf16.h>
#include <stdint.h>
#include <stddef.h>

#define B_ 8
#define S_ 2048
#define E_ 1024
#define H_ 128
#define NR_ (B_ * S_)   // 16384 total q-rows

typedef __attribute__((ext_vector_type(8))) short short8;   // 8 x bf16 (4 VGPRs)
typedef __attribute__((ext_vector_type(4))) short short4v;
typedef __attribute__((ext_vector_type(4))) float f32x4;

__device__ __forceinline__ short f2bf(float f){
  uint32_t u = __builtin_bit_cast(uint32_t, f);
  u = (u + 0x7FFFu + ((u >> 16) & 1u)) >> 16;   // RNE
  return (short)(uint16_t)u;
}

// 8 f32 -> 8 bf16 via v_cvt_pk_bf16_f32 (no builtin on gfx950; RNE)
__device__ __forceinline__ short8 pack8(f32x4 a, f32x4 b){
  union { short8 s; uint32_t u[4]; } r;
  asm("v_cvt_pk_bf16_f32 %0, %1, %2" : "=v"(r.u[0]) : "v"(a[0]), "v"(a[1]));
  asm("v_cvt_pk_bf16_f32 %0, %1, %2" : "=v"(r.u[1]) : "v"(a[2]), "v"(a[3]));
  asm("v_cvt_pk_bf16_f32 %0, %1, %2" : "=v"(r.u[2]) : "v"(b[0]), "v"(b[1]));
  asm("v_cvt_pk_bf16_f32 %0, %1, %2" : "=v"(r.u[3]) : "v"(b[2]), "v"(b[3]));
  return r.s;
}

#define GLOBAL_AS __attribute__((address_space(1)))
#define LDS_AS    __attribute__((address_space(3)))
__device__ __forceinline__ void async16(const void* g, void* l){
  __builtin_amdgcn_global_load_lds((const GLOBAL_AS uint32_t*)g,
                                   (LDS_AS uint32_t*)l, 16, 0, 0);
}

// ---------------------------------------------------------------------------
// prep = pack_w only (the x cast is now fused into qkv_gemm's A-staging).
// w [E][H] f32 -> wt [3H][E] bf16.  384 blocks.
// ---------------------------------------------------------------------------
__global__ void prep(const float* __restrict__ wq, const float* __restrict__ wk,
                     const float* __restrict__ wv, short* __restrict__ wt){
  __shared__ float t[32][33];
  int idx = blockIdx.x;
  int hb  = idx & 3;
  int eb  = (idx >> 2) & 31;
  int w   = idx >> 7;
  const float* src = (w == 0) ? wq : (w == 1) ? wk : wv;
  int c  = threadIdx.x & 31;
  int r0 = threadIdx.x >> 5;
#pragma unroll
  for (int i = 0; i < 4; i++){
    int r = r0 * 4 + i;
    t[r][c] = src[(size_t)(eb * 32 + r) * H_ + hb * 32 + c];
  }
  __syncthreads();
#pragma unroll
  for (int i = 0; i < 4; i++){
    int r = r0 * 4 + i;
    wt[(size_t)(w * 128 + hb * 32 + r) * E_ + eb * 32 + c] = f2bf(t[c][r]);
  }
}

// ---------------------------------------------------------------------------
// QKV GEMM v7 — m97-pattern 128x128 tile. A (x) is now read DIRECTLY as f32
// and converted to bf16 during reg-staging (global f32x4 -> cvt_pk ->
// ds_write_b128 into the SAME swizzled LDS layout as v6's async16 path, so
// fragment reads/MFMA are unchanged). B (wt bf16) keeps global_load_lds.
// A-loads issue right after the barrier; converts+writes after the MFMA
// phase so load latency hides under compute. V transpose fused in epilogue.
// ---------------------------------------------------------------------------
__launch_bounds__(256)
__global__ void qkv_gemm(const float* __restrict__ x, const short* __restrict__ wt,
                         short* __restrict__ qm, short* __restrict__ km,
                         short* __restrict__ vt){
  __shared__ __align__(16) short smem[16896];   // 33792 B: stage 32 KB | vtile 33 KB
  const int wave = threadIdx.x >> 6;
  const int lane = threadIdx.x & 63;
  const int l16  = lane & 15;
  const int quad = lane >> 4;
  const int nb   = blockIdx.x;        // 0..2  (q,k,v)
  const int m0   = blockIdx.y * 128;
  const int n0   = nb * 128;

  f32x4 acc[4][4];
#pragma unroll
  for (int i = 0; i < 4; i++)
#pragma unroll
    for (int j = 0; j < 4; j++) acc[i][j] = (f32x4)(0.0f);

  // per-lane A staging geometry (chunk c covers rows c*16..c*16+15, XOR-swizzled
  // 8-col groups; identical placement to v6's async16: base + c*1024 + lane*16)
  int cA[2], rA[2], qA[2];
#pragma unroll
  for (int i = 0; i < 2; i++){
    cA[i] = wave * 2 + i;
    rA[i] = cA[i] * 16 + (lane >> 2);
    qA[i] = ((lane & 3) ^ ((rA[i] >> 1) & 3)) & 3;
  }

  f32x4 a0[2], a1[2];

#define A_LOAD(k0)                                                            \
  {                                                                           \
    _Pragma("unroll")                                                         \
    for (int i = 0; i < 2; i++){                                              \
      const float* s_ = x + (size_t)(m0 + rA[i]) * E_ + (k0) + qA[i] * 8;     \
      a0[i] = *(const f32x4*)s_;                                              \
      a1[i] = *(const f32x4*)(s_ + 4);                                        \
    }                                                                         \
  }

#define A_WRITE(buf)                                                          \
  {                                                                           \
    _Pragma("unroll")                                                         \
    for (int i = 0; i < 2; i++)                                               \
      *(short8*)((char*)(smem + (buf) * 4096) + cA[i] * 1024 + lane * 16) =   \
          pack8(a0[i], a1[i]);                                                \
  }

#define B_STAGE(buf, k0)                                                      \
  {                                                                           \
    _Pragma("unroll")                                                         \
    for (int i = 0; i < 2; i++){                                              \
      int c = wave * 2 + i;                                                   \
      int r = c * 16 + (lane >> 2);                                           \
      int q = ((lane & 3) ^ ((r >> 1) & 3)) & 3;                              \
      async16(wt + (size_t)(n0 + r) * E_ + (k0) + q * 8,                      \
              (char*)(smem + 8192 + (buf) * 4096) + c * 1024);                \
    }                                                                         \
  }

  A_LOAD(0)
  B_STAGE(0, 0)
  A_WRITE(0)
  for (int ks = 0; ks < 32; ks++){
    const int k0 = ks * 32;
    __syncthreads();
    if (ks < 31){
      A_LOAD(k0 + 32)                 // f32 loads in flight across MFMA phase
      B_STAGE((ks + 1) & 1, k0 + 32)
    }

    const short* a = smem + (ks & 1) * 4096;
    const short* b = smem + 8192 + (ks & 1) * 4096;
    short8 af[4], bf[4];
#pragma unroll
    for (int t = 0; t < 4; t++){
      int ra = (wave & 1) * 64 + t * 16 + l16;
      int pa = (quad ^ ((ra >> 1) & 3)) & 3;
      af[t] = *(const short8*)(a + ra * 32 + pa * 8);
      int rb = (wave >> 1) * 64 + t * 16 + l16;
      int pb = (quad ^ ((rb >> 1) & 3)) & 3;
      bf[t] = *(const short8*)(b + rb * 32 + pb * 8);
    }
#pragma unroll
    for (int mt = 0; mt < 4; mt++)
#pragma unroll
      for (int nt = 0; nt < 4; nt++)
        acc[mt][nt] = __builtin_amdgcn_mfma_f32_16x16x32_bf16(af[mt], bf[nt], acc[mt][nt], 0, 0, 0);

    if (ks < 31){
      A_WRITE((ks + 1) & 1)           // cvt+ds_write to the buffer read next iter
    }
  }
#undef A_LOAD
#undef A_WRITE
#undef B_STAGE

  if (nb != 2){
    short* dst = (nb == 0) ? qm : km;
#pragma unroll
    for (int mt = 0; mt < 4; mt++)
#pragma unroll
      for (int nt = 0; nt < 4; nt++){
        int row = m0 + (wave & 1) * 64 + mt * 16 + quad * 4;
        int col = (wave >> 1) * 64 + nt * 16 + l16;
#pragma unroll
        for (int r = 0; r < 4; r++)
          dst[(size_t)(row + r) * H_ + col] = f2bf(acc[mt][nt][r]);
      }
  } else {
    __syncthreads();                            // stage bufs dead; reuse as vtile
#pragma unroll
    for (int mt = 0; mt < 4; mt++)
#pragma unroll
      for (int nt = 0; nt < 4; nt++){
        int scol = (wave & 1) * 64 + mt * 16 + quad * 4;   // s within tile
        int hrow = (wave >> 1) * 64 + nt * 16 + l16;       // h
        short4v t4;
#pragma unroll
        for (int r = 0; r < 4; r++) t4[r] = f2bf(acc[mt][nt][r]);
        *(short4v*)(smem + hrow * 132 + scol) = t4;
      }
    __syncthreads();
    int h   = threadIdx.x >> 1;
    int s0  = (threadIdx.x & 1) * 64;
    int bb_ = m0 >> 11;                         // batch
    short* dstv = vt + ((size_t)bb_ * H_ + h) * S_ + (m0 & (S_ - 1)) + s0;
    const short* srcv = smem + h * 132 + s0;
#pragma unroll
    for (int i = 0; i < 8; i++)
      *(short8*)(dstv + i * 8) = *(const short8*)(srcv + i * 8);
  }
}

// ---------------------------------------------------------------------------
// Attention v5: 512 threads (8 waves), 128 q-rows/block -> K/V staging
// amortized 2x vs v4. bf16 pbuf (18 KB) with the dropout 1/0.9 scale folded
// into the o-epilogue so the P-pack is a pure bf16 select. LDS 50 KB.
// No online max (|s|<2); per-lane l partials; XOR-swizzled DMA staging.
// ---------------------------------------------------------------------------
__launch_bounds__(512)
__global__ void attn(const short* __restrict__ qm, const short* __restrict__ km,
                     const short* __restrict__ vtm, const float* __restrict__ du,
                     float* __restrict__ po, float* __restrict__ pl,
                     float* __restrict__ out, int split){
  const int wave = threadIdx.x >> 6;
  const int lane = threadIdx.x & 63;
  const int l16  = lane & 15;
  const int quad = lane >> 4;
  const int sp   = blockIdx.x & (split - 1);    // split is 1/2/4
  const int rbk  = blockIdx.x / split;
  const int b    = rbk >> 4;                    // 16 row-blocks per batch
  const int m0   = (rbk & 15) * 128 + wave * 16;
  const int seg  = S_ / split;

  const short* qb  = qm  + ((size_t)b * S_ + m0) * H_;
  const short* kb  = km  + (size_t)b * S_ * H_;
  const short* vb  = vtm + (size_t)b * H_ * S_;
  const float* dub = du  + ((size_t)b * S_ + m0) * S_;

  __shared__ __align__(16) short kls[8192];     // [64 key][128 k] swizzled
  __shared__ __align__(16) short vls[8192];     // [128 h][64 t]  swizzled
  __shared__ short pbuf[8][16][72];             // bf16 P round-trip, per-wave
  short* pb = &pbuf[wave][0][0];

  short8 qf[4];
#pragma unroll
  for (int kc = 0; kc < 4; kc++)
    qf[kc] = *(const short8*)(qb + (size_t)l16 * H_ + kc * 32 + quad * 8);

  f32x4 o[8];
#pragma unroll
  for (int ht = 0; ht < 8; ht++) o[ht] = (f32x4)(0.0f);
  float lpart[4] = {0.f, 0.f, 0.f, 0.f};

  const float SC2  = 0.045084220f;              // log2(e) / 32
  const float KINV = 1.0f / 0.9f;

  const int tbeg = sp * seg;
  for (int t0 = tbeg; t0 < tbeg + seg; t0 += 64){
    // ---- stage K (16 chunks) + V (16 chunks), 2+2 per wave ----
#pragma unroll
    for (int i = 0; i < 2; i++){
      int c = wave * 2 + i;
      int r = c * 4 + (lane >> 4);
      int s = lane & 15;
      int q = (s & 8) | ((s ^ r) & 7);
      async16(kb + (size_t)(t0 + r) * H_ + q * 8, (char*)kls + c * 1024);
    }
#pragma unroll
    for (int i = 0; i < 2; i++){
      int c = wave * 2 + i;
      int r = c * 8 + (lane >> 3);
      int s = lane & 7;
      int q = (s ^ r) & 7;
      async16(vb + (size_t)r * S_ + t0 + q * 8, (char*)vls + c * 1024);
    }
    __syncthreads();

    // du loads (unique data) issued early to overlap QK phase
    const float* dp = dub + (size_t)l16 * S_ + t0 + quad * 8;
    f32x4 u0 = *(const f32x4*)(dp);
    f32x4 u1 = *(const f32x4*)(dp + 4);
    f32x4 u2 = *(const f32x4*)(dp + 32);
    f32x4 u3 = *(const f32x4*)(dp + 36);

    // ---- S = Q K^T ----
    f32x4 s[4];
#pragma unroll
    for (int nt = 0; nt < 4; nt++) s[nt] = (f32x4)(0.0f);
#pragma unroll
    for (int nt = 0; nt < 4; nt++){
      int row = nt * 16 + l16;
#pragma unroll
      for (int kc = 0; kc < 4; kc++){
        int q  = kc * 4 + quad;
        int ph = (q & 8) | ((q ^ row) & 7);
        short8 bf = *(const short8*)((const char*)kls + row * 256 + ph * 16);
        s[nt] = __builtin_amdgcn_mfma_f32_16x16x32_bf16(qf[kc], bf, s[nt], 0, 0, 0);
      }
    }

    // ---- p = exp2(s*SC2); per-lane l; stage bf16 P to pbuf (C-layout) ----
#pragma unroll
    for (int nt = 0; nt < 4; nt++)
#pragma unroll
      for (int r = 0; r < 4; r++){
        float p = exp2f(s[nt][r] * SC2);
        lpart[r] += p;
        pb[(quad * 4 + r) * 72 + nt * 16 + l16] = f2bf(p);
      }

    __builtin_amdgcn_sched_barrier(0);
    __builtin_amdgcn_s_waitcnt(0xC07F);         // lgkmcnt(0) only
    __builtin_amdgcn_sched_barrier(0);

    // ---- A-layout read + dropout select (scale folded to epilogue) ----
    const short* pr = pb + l16 * 72 + quad * 8;
    short8 pb0 = *(const short8*)(pr);
    short8 pb1 = *(const short8*)(pr + 32);
    short8 pa0, pa1;
#pragma unroll
    for (int j = 0; j < 4; j++){
      pa0[j]     = (u0[j] >= 0.1f) ? pb0[j]     : (short)0;
      pa0[j + 4] = (u1[j] >= 0.1f) ? pb0[j + 4] : (short)0;
      pa1[j]     = (u2[j] >= 0.1f) ? pb1[j]     : (short)0;
      pa1[j + 4] = (u3[j] >= 0.1f) ? pb1[j + 4] : (short)0;
    }

    // ---- O += P V ----
#pragma unroll
    for (int ht = 0; ht < 8; ht++){
      int row = ht * 16 + l16;
#pragma unroll
      for (int half = 0; half < 2; half++){
        int q  = half * 4 + quad;
        int ph = (q ^ row) & 7;
        short8 vf = *(const short8*)((const char*)vls + row * 128 + ph * 16);
        o[ht] = __builtin_amdgcn_mfma_f32_16x16x32_bf16(half ? pa1 : pa0, vf, o[ht], 0, 0, 0);
      }
    }
    __syncthreads();                            // protect kls/vls rewrite
  }

  float lrow[4];
#pragma unroll
  for (int r = 0; r < 4; r++){
    float v = lpart[r];
    v += __shfl_xor(v, 1);
    v += __shfl_xor(v, 2);
    v += __shfl_xor(v, 4);
    v += __shfl_xor(v, 8);
    lrow[r] = v;
  }

  if (split == 1){
    float* op = out + ((size_t)b * S_ + m0) * H_;
#pragma unroll
    for (int ht = 0; ht < 8; ht++)
#pragma unroll
      for (int r = 0; r < 4; r++)
        op[(size_t)(quad * 4 + r) * H_ + ht * 16 + l16] = o[ht][r] * KINV / lrow[r];
  } else {
#pragma unroll
    for (int r = 0; r < 4; r++){
      size_t R = (size_t)b * S_ + m0 + quad * 4 + r;
#pragma unroll
      for (int ht = 0; ht < 8; ht++)
        po[((size_t)sp * NR_ + R) * H_ + ht * 16 + l16] = o[ht][r] * KINV;
      if (l16 == 0) pl[(size_t)sp * NR_ + R] = lrow[r];
    }
  }
}

// ---------------------------------------------------------------------------
__global__ void combine(const float* __restrict__ po, const float* __restrict__ pl,
                        float* __restrict__ out, int split){
  int row = blockIdx.x;
  int col = threadIdx.x;
  float num = 0.f, den = 0.f;
  for (int s = 0; s < split; s++){
    num += po[((size_t)s * NR_ + row) * H_ + col];
    den += pl[(size_t)s * NR_ + row];
  }
  out[(size_t)row * H_ + col] = num / den;
}

// ---------------------------------------------------------------------------
extern "C" void kernel_launch(void* const* d_in, const int* in_sizes, int n_in,
                              void* d_out, int out_size, void* d_ws, size_t ws_size,
                              hipStream_t stream){
  const float* x  = (const float*)d_in[0];
  const float* wq = (const float*)d_in[1];
  const float* wk = (const float*)d_in[2];
  const float* wv = (const float*)d_in[3];
  const float* du = (const float*)d_in[4];
  float* out = (float*)d_out;

  const size_t MiB = 1048576;
  char* ws = (char*)d_ws;
  short* qm = (short*)(ws);                      // 4 MiB
  short* km = (short*)(ws + 4 * MiB);            // 4 MiB
  short* vt = (short*)(ws + 8 * MiB);            // 4 MiB
  short* wt = (short*)(ws + 44 * MiB);           // 768 KiB (xb slot now unused)
  float* pl = (float*)(ws + 45 * MiB);           // split*64 KiB
  float* po = (float*)(ws + 45 * MiB + 524288);  // split*8 MiB

  size_t base  = 45 * MiB + 524288;
  size_t needA = base + 32 * MiB;
  size_t needB = base + 16 * MiB;
  int split = (ws_size >= needA) ? 4 : (ws_size >= needB) ? 2 : 1;

  hipLaunchKernelGGL(prep,     dim3(384),         dim3(256), 0, stream, wq, wk, wv, wt);
  hipLaunchKernelGGL(qkv_gemm, dim3(3, 128),      dim3(256), 0, stream, x, wt, qm, km, vt);
  hipLaunchKernelGGL(attn,     dim3(128 * split), dim3(512), 0, stream,
                     qm, km, vt, du, po, pl, out, split);
  if (split > 1)
    hipLaunchKernelGGL(combine, dim3(NR_), dim3(H_), 0, stream, po, pl, out, split);
}

// Round 4
// 290.166 us; speedup vs baseline: 1.0109x; 1.0109x over previous
//
#include <hip/hip_runtime.h>
#include <hip/hip_bf16.h>
#include <stdint.h>
#include <stddef.h>

#define B_ 8
#define S_ 2048
#define E_ 1024
#define H_ 128
#define NR_ (B_ * S_)   // 16384 total q-rows

typedef __attribute__((ext_vector_type(8))) short short8;   // 8 x bf16 (4 VGPRs)
typedef __attribute__((ext_vector_type(4))) short short4v;
typedef __attribute__((ext_vector_type(4))) float f32x4;

__device__ __forceinline__ short f2bf(float f){
  uint32_t u = __builtin_bit_cast(uint32_t, f);
  u = (u + 0x7FFFu + ((u >> 16) & 1u)) >> 16;   // RNE
  return (short)(uint16_t)u;
}

// 8 f32 -> 8 bf16 via v_cvt_pk_bf16_f32 (no builtin on gfx950; RNE)
__device__ __forceinline__ short8 pack8(f32x4 a, f32x4 b){
  union { short8 s; uint32_t u[4]; } r;
  asm("v_cvt_pk_bf16_f32 %0, %1, %2" : "=v"(r.u[0]) : "v"(a[0]), "v"(a[1]));
  asm("v_cvt_pk_bf16_f32 %0, %1, %2" : "=v"(r.u[1]) : "v"(a[2]), "v"(a[3]));
  asm("v_cvt_pk_bf16_f32 %0, %1, %2" : "=v"(r.u[2]) : "v"(b[0]), "v"(b[1]));
  asm("v_cvt_pk_bf16_f32 %0, %1, %2" : "=v"(r.u[3]) : "v"(b[2]), "v"(b[3]));
  return r.s;
}

#define GLOBAL_AS __attribute__((address_space(1)))
#define LDS_AS    __attribute__((address_space(3)))
__device__ __forceinline__ void async16(const void* g, void* l){
  __builtin_amdgcn_global_load_lds((const GLOBAL_AS uint32_t*)g,
                                   (LDS_AS uint32_t*)l, 16, 0, 0);
}

// ---------------------------------------------------------------------------
// prep = pack_w only. w [E][H] f32 -> wt [3H][E] bf16.  384 blocks.
// ---------------------------------------------------------------------------
__global__ void prep(const float* __restrict__ wq, const float* __restrict__ wk,
                     const float* __restrict__ wv, short* __restrict__ wt){
  __shared__ float t[32][33];
  int idx = blockIdx.x;
  int hb  = idx & 3;
  int eb  = (idx >> 2) & 31;
  int w   = idx >> 7;
  const float* src = (w == 0) ? wq : (w == 1) ? wk : wv;
  int c  = threadIdx.x & 31;
  int r0 = threadIdx.x >> 5;
#pragma unroll
  for (int i = 0; i < 4; i++){
    int r = r0 * 4 + i;
    t[r][c] = src[(size_t)(eb * 32 + r) * H_ + hb * 32 + c];
  }
  __syncthreads();
#pragma unroll
  for (int i = 0; i < 4; i++){
    int r = r0 * 4 + i;
    wt[(size_t)(w * 128 + hb * 32 + r) * E_ + eb * 32 + c] = f2bf(t[c][r]);
  }
}

// ---------------------------------------------------------------------------
// QKV GEMM v7 (EXACT R1-proven version, PASSED) — fused f32->bf16 A-staging,
// prefetch distance 1, single A register set. Reverted from v8 (distance-2)
// which is the prime suspect for the R2/R3 correctness failures.
// ---------------------------------------------------------------------------
__launch_bounds__(256)
__global__ void qkv_gemm(const float* __restrict__ x, const short* __restrict__ wt,
                         short* __restrict__ qm, short* __restrict__ km,
                         short* __restrict__ vt){
  __shared__ __align__(16) short smem[16896];   // 33792 B: stage 32 KB | vtile 33 KB
  const int wave = threadIdx.x >> 6;
  const int lane = threadIdx.x & 63;
  const int l16  = lane & 15;
  const int quad = lane >> 4;
  const int nb   = blockIdx.x;        // 0..2  (q,k,v)
  const int m0   = blockIdx.y * 128;
  const int n0   = nb * 128;

  f32x4 acc[4][4];
#pragma unroll
  for (int i = 0; i < 4; i++)
#pragma unroll
    for (int j = 0; j < 4; j++) acc[i][j] = (f32x4)(0.0f);

  // per-lane A staging geometry (chunk c covers rows c*16..c*16+15, XOR-swizzled
  // 8-col groups; identical placement to the async16 layout: c*1024 + lane*16)
  int cA[2], rA[2], qA[2];
#pragma unroll
  for (int i = 0; i < 2; i++){
    cA[i] = wave * 2 + i;
    rA[i] = cA[i] * 16 + (lane >> 2);
    qA[i] = ((lane & 3) ^ ((rA[i] >> 1) & 3)) & 3;
  }

  f32x4 a0[2], a1[2];

#define A_LOAD(k0)                                                            \
  {                                                                           \
    _Pragma("unroll")                                                         \
    for (int i = 0; i < 2; i++){                                              \
      const float* s_ = x + (size_t)(m0 + rA[i]) * E_ + (k0) + qA[i] * 8;     \
      a0[i] = *(const f32x4*)s_;                                              \
      a1[i] = *(const f32x4*)(s_ + 4);                                        \
    }                                                                         \
  }

#define A_WRITE(buf)                                                          \
  {                                                                           \
    _Pragma("unroll")                                                         \
    for (int i = 0; i < 2; i++)                                               \
      *(short8*)((char*)(smem + (buf) * 4096) + cA[i] * 1024 + lane * 16) =   \
          pack8(a0[i], a1[i]);                                                \
  }

#define B_STAGE(buf, k0)                                                      \
  {                                                                           \
    _Pragma("unroll")                                                         \
    for (int i = 0; i < 2; i++){                                              \
      int c = wave * 2 + i;                                                   \
      int r = c * 16 + (lane >> 2);                                           \
      int q = ((lane & 3) ^ ((r >> 1) & 3)) & 3;                              \
      async16(wt + (size_t)(n0 + r) * E_ + (k0) + q * 8,                      \
              (char*)(smem + 8192 + (buf) * 4096) + c * 1024);                \
    }                                                                         \
  }

  A_LOAD(0)
  B_STAGE(0, 0)
  A_WRITE(0)
  for (int ks = 0; ks < 32; ks++){
    const int k0 = ks * 32;
    __syncthreads();
    if (ks < 31){
      A_LOAD(k0 + 32)                 // f32 loads in flight across MFMA phase
      B_STAGE((ks + 1) & 1, k0 + 32)
    }

    const short* a = smem + (ks & 1) * 4096;
    const short* b = smem + 8192 + (ks & 1) * 4096;
    short8 af[4], bf[4];
#pragma unroll
    for (int t = 0; t < 4; t++){
      int ra = (wave & 1) * 64 + t * 16 + l16;
      int pa = (quad ^ ((ra >> 1) & 3)) & 3;
      af[t] = *(const short8*)(a + ra * 32 + pa * 8);
      int rb = (wave >> 1) * 64 + t * 16 + l16;
      int pb = (quad ^ ((rb >> 1) & 3)) & 3;
      bf[t] = *(const short8*)(b + rb * 32 + pb * 8);
    }
#pragma unroll
    for (int mt = 0; mt < 4; mt++)
#pragma unroll
      for (int nt = 0; nt < 4; nt++)
        acc[mt][nt] = __builtin_amdgcn_mfma_f32_16x16x32_bf16(af[mt], bf[nt], acc[mt][nt], 0, 0, 0);

    if (ks < 31){
      A_WRITE((ks + 1) & 1)           // cvt+ds_write to the buffer read next iter
    }
  }
#undef A_LOAD
#undef A_WRITE
#undef B_STAGE

  if (nb != 2){
    short* dst = (nb == 0) ? qm : km;
#pragma unroll
    for (int mt = 0; mt < 4; mt++)
#pragma unroll
      for (int nt = 0; nt < 4; nt++){
        int row = m0 + (wave & 1) * 64 + mt * 16 + quad * 4;
        int col = (wave >> 1) * 64 + nt * 16 + l16;
#pragma unroll
        for (int r = 0; r < 4; r++)
          dst[(size_t)(row + r) * H_ + col] = f2bf(acc[mt][nt][r]);
      }
  } else {
    __syncthreads();                            // stage bufs dead; reuse as vtile
#pragma unroll
    for (int mt = 0; mt < 4; mt++)
#pragma unroll
      for (int nt = 0; nt < 4; nt++){
        int scol = (wave & 1) * 64 + mt * 16 + quad * 4;   // s within tile
        int hrow = (wave >> 1) * 64 + nt * 16 + l16;       // h
        short4v t4;
#pragma unroll
        for (int r = 0; r < 4; r++) t4[r] = f2bf(acc[mt][nt][r]);
        *(short4v*)(smem + hrow * 132 + scol) = t4;
      }
    __syncthreads();
    int h   = threadIdx.x >> 1;
    int s0  = (threadIdx.x & 1) * 64;
    int bb_ = m0 >> 11;                         // batch
    short* dstv = vt + ((size_t)bb_ * H_ + h) * S_ + (m0 & (S_ - 1)) + s0;
    const short* srcv = smem + h * 132 + s0;
#pragma unroll
    for (int i = 0; i < 8; i++)
      *(short8*)(dstv + i * 8) = *(const short8*)(srcv + i * 8);
  }
}

// ---------------------------------------------------------------------------
// Attention v6b (UNCHANGED from R3): pipelined ISSUE, R1-proven FENCING
// (two __syncthreads/iter, full vmcnt(0)+lgkmcnt(0) drains).
//  - K double-buffered: prefetch for tile it+1 issued BEFORE the QK phase of
//    tile it, drained at the mid __syncthreads.
//  - V staged at iter top, consumed after QK, published by mid __syncthreads.
// LDS 66 KB -> 2 blocks/CU.
// ---------------------------------------------------------------------------
__launch_bounds__(512)
__global__ void attn(const short* __restrict__ qm, const short* __restrict__ km,
                     const short* __restrict__ vtm, const float* __restrict__ du,
                     float* __restrict__ po, float* __restrict__ pl,
                     float* __restrict__ out, int split){
  const int wave = threadIdx.x >> 6;
  const int lane = threadIdx.x & 63;
  const int l16  = lane & 15;
  const int quad = lane >> 4;
  const int sp   = blockIdx.x & (split - 1);    // split is 1/2/4
  const int rbk  = blockIdx.x / split;
  const int b    = rbk >> 4;                    // 16 row-blocks per batch
  const int m0   = (rbk & 15) * 128 + wave * 16;
  const int seg  = S_ / split;

  const short* qb  = qm  + ((size_t)b * S_ + m0) * H_;
  const short* kb  = km  + (size_t)b * S_ * H_;
  const short* vb  = vtm + (size_t)b * H_ * S_;
  const float* dub = du  + ((size_t)b * S_ + m0) * S_;

  __shared__ __align__(16) short kls[2][8192];  // dbuf [64 key][128 k] swizzled
  __shared__ __align__(16) short vls[8192];     // [128 h][64 t]  swizzled
  __shared__ short pbuf[8][16][72];             // bf16 P round-trip, per-wave
  short* pb = &pbuf[wave][0][0];

  short8 qf[4];
#pragma unroll
  for (int kc = 0; kc < 4; kc++)
    qf[kc] = *(const short8*)(qb + (size_t)l16 * H_ + kc * 32 + quad * 8);

  f32x4 o[8];
#pragma unroll
  for (int ht = 0; ht < 8; ht++) o[ht] = (f32x4)(0.0f);
  float lpart[4] = {0.f, 0.f, 0.f, 0.f};

  const float SC2  = 0.045084220f;              // log2(e) / 32
  const float KINV = 1.0f / 0.9f;

#define K_STAGE(bufi, ts)                                                     \
  {                                                                           \
    _Pragma("unroll")                                                         \
    for (int i = 0; i < 2; i++){                                              \
      int c = wave * 2 + i;                                                   \
      int r = c * 4 + (lane >> 4);                                            \
      int s = lane & 15;                                                      \
      int q = (s & 8) | ((s ^ r) & 7);                                        \
      async16(kb + (size_t)((ts) + r) * H_ + q * 8,                           \
              (char*)kls + (bufi) * 16384 + c * 1024);                        \
    }                                                                         \
  }

  const int tbeg = sp * seg;
  const int nIt  = seg >> 6;

  K_STAGE(0, tbeg)                              // prologue: stage tile 0

  for (int it = 0; it < nIt; ++it){
    const int t0  = tbeg + (it << 6);
    const int cur = it & 1;

    __syncthreads();                            // prev PV done -> vls rewritable

    // ---- V stage (current tile) ----
#pragma unroll
    for (int i = 0; i < 2; i++){
      int c = wave * 2 + i;
      int r = c * 8 + (lane >> 3);
      int s = lane & 7;
      int q = (s ^ r) & 7;
      async16(vb + (size_t)r * S_ + t0 + q * 8, (char*)vls + c * 1024);
    }

    // ---- du loads (unique data), consumed after QK ----
    const float* dp = dub + (size_t)l16 * S_ + t0 + quad * 8;
    f32x4 u0 = *(const f32x4*)(dp);
    f32x4 u1 = *(const f32x4*)(dp + 4);
    f32x4 u2 = *(const f32x4*)(dp + 32);
    f32x4 u3 = *(const f32x4*)(dp + 36);

    // ---- K prefetch (next tile; wraps harmlessly on last iter) ----
    const int nt0 = (it + 1 < nIt) ? (t0 + 64) : tbeg;
    K_STAGE(cur ^ 1, nt0)

    // ---- S = Q K^T  (reads kls[cur], staged last iter, drained at mid sync)
    f32x4 s[4];
#pragma unroll
    for (int nt = 0; nt < 4; nt++) s[nt] = (f32x4)(0.0f);
#pragma unroll
    for (int nt = 0; nt < 4; nt++){
      int row = nt * 16 + l16;
#pragma unroll
      for (int kc = 0; kc < 4; kc++){
        int q  = kc * 4 + quad;
        int ph = (q & 8) | ((q ^ row) & 7);
        short8 bf = *(const short8*)((const char*)kls + cur * 16384 + row * 256 + ph * 16);
        s[nt] = __builtin_amdgcn_mfma_f32_16x16x32_bf16(qf[kc], bf, s[nt], 0, 0, 0);
      }
    }

    // ---- p = exp2(s*SC2); per-lane l; stage bf16 P to pbuf (C-layout) ----
#pragma unroll
    for (int nt = 0; nt < 4; nt++)
#pragma unroll
      for (int r = 0; r < 4; r++){
        float p = exp2f(s[nt][r] * SC2);
        lpart[r] += p;
        pb[(quad * 4 + r) * 72 + nt * 16 + l16] = f2bf(p);
      }

    __builtin_amdgcn_sched_barrier(0);
    __builtin_amdgcn_s_waitcnt(0xC07F);         // lgkmcnt(0) only
    __builtin_amdgcn_sched_barrier(0);

    // ---- A-layout read + dropout select (scale folded to epilogue) ----
    const short* pr = pb + l16 * 72 + quad * 8;
    short8 pb0 = *(const short8*)(pr);
    short8 pb1 = *(const short8*)(pr + 32);
    short8 pa0, pa1;
#pragma unroll
    for (int j = 0; j < 4; j++){
      pa0[j]     = (u0[j] >= 0.1f) ? pb0[j]     : (short)0;
      pa0[j + 4] = (u1[j] >= 0.1f) ? pb0[j + 4] : (short)0;
      pa1[j]     = (u2[j] >= 0.1f) ? pb1[j]     : (short)0;
      pa1[j + 4] = (u3[j] >= 0.1f) ? pb1[j + 4] : (short)0;
    }

    __syncthreads();                            // mid: publish V (full drain)

    // ---- O += P V ----
#pragma unroll
    for (int ht = 0; ht < 8; ht++){
      int row = ht * 16 + l16;
#pragma unroll
      for (int half = 0; half < 2; half++){
        int q  = half * 4 + quad;
        int ph = (q ^ row) & 7;
        short8 vf = *(const short8*)((const char*)vls + row * 128 + ph * 16);
        o[ht] = __builtin_amdgcn_mfma_f32_16x16x32_bf16(half ? pa1 : pa0, vf, o[ht], 0, 0, 0);
      }
    }
  }
#undef K_STAGE

  float lrow[4];
#pragma unroll
  for (int r = 0; r < 4; r++){
    float v = lpart[r];
    v += __shfl_xor(v, 1);
    v += __shfl_xor(v, 2);
    v += __shfl_xor(v, 4);
    v += __shfl_xor(v, 8);
    lrow[r] = v;
  }

  if (split == 1){
    float* op = out + ((size_t)b * S_ + m0) * H_;
#pragma unroll
    for (int ht = 0; ht < 8; ht++)
#pragma unroll
      for (int r = 0; r < 4; r++)
        op[(size_t)(quad * 4 + r) * H_ + ht * 16 + l16] = o[ht][r] * KINV / lrow[r];
  } else {
#pragma unroll
    for (int r = 0; r < 4; r++){
      size_t R = (size_t)b * S_ + m0 + quad * 4 + r;
#pragma unroll
      for (int ht = 0; ht < 8; ht++)
        po[((size_t)sp * NR_ + R) * H_ + ht * 16 + l16] = o[ht][r] * KINV;
      if (l16 == 0) pl[(size_t)sp * NR_ + R] = lrow[r];
    }
  }
}

// ---------------------------------------------------------------------------
__global__ void combine(const float* __restrict__ po, const float* __restrict__ pl,
                        float* __restrict__ out, int split){
  int row = blockIdx.x;
  int col = threadIdx.x;
  float num = 0.f, den = 0.f;
  for (int s = 0; s < split; s++){
    num += po[((size_t)s * NR_ + row) * H_ + col];
    den += pl[(size_t)s * NR_ + row];
  }
  out[(size_t)row * H_ + col] = num / den;
}

// ---------------------------------------------------------------------------
extern "C" void kernel_launch(void* const* d_in, const int* in_sizes, int n_in,
                              void* d_out, int out_size, void* d_ws, size_t ws_size,
                              hipStream_t stream){
  const float* x  = (const float*)d_in[0];
  const float* wq = (const float*)d_in[1];
  const float* wk = (const float*)d_in[2];
  const float* wv = (const float*)d_in[3];
  const float* du = (const float*)d_in[4];
  float* out = (float*)d_out;

  const size_t MiB = 1048576;
  char* ws = (char*)d_ws;
  short* qm = (short*)(ws);                      // 4 MiB
  short* km = (short*)(ws + 4 * MiB);            // 4 MiB
  short* vt = (short*)(ws + 8 * MiB);            // 4 MiB
  short* wt = (short*)(ws + 44 * MiB);           // 768 KiB
  float* pl = (float*)(ws + 45 * MiB);           // split*64 KiB
  float* po = (float*)(ws + 45 * MiB + 524288);  // split*8 MiB

  size_t base  = 45 * MiB + 524288;
  size_t needA = base + 32 * MiB;
  size_t needB = base + 16 * MiB;
  int split = (ws_size >= needA) ? 4 : (ws_size >= needB) ? 2 : 1;

  hipLaunchKernelGGL(prep,     dim3(384),         dim3(256), 0, stream, wq, wk, wv, wt);
  hipLaunchKernelGGL(qkv_gemm, dim3(3, 128),      dim3(256), 0, stream, x, wt, qm, km, vt);
  hipLaunchKernelGGL(attn,     dim3(128 * split), dim3(512), 0, stream,
                     qm, km, vt, du, po, pl, out, split);
  if (split > 1)
    hipLaunchKernelGGL(combine, dim3(NR_), dim3(H_), 0, stream, po, pl, out, split);
}

// Round 5
// 287.997 us; speedup vs baseline: 1.0185x; 1.0075x over previous
//
#include <hip/hip_runtime.h>
#include <hip/hip_bf16.h>
#include <stdint.h>
#include <stddef.h>

#define B_ 8
#define S_ 2048
#define E_ 1024
#define H_ 128
#define NR_ (B_ * S_)   // 16384 total q-rows

typedef __attribute__((ext_vector_type(8))) short short8;   // 8 x bf16 (4 VGPRs)
typedef __attribute__((ext_vector_type(4))) short short4v;
typedef __attribute__((ext_vector_type(4))) float f32x4;

__device__ __forceinline__ short f2bf(float f){
  uint32_t u = __builtin_bit_cast(uint32_t, f);
  u = (u + 0x7FFFu + ((u >> 16) & 1u)) >> 16;   // RNE
  return (short)(uint16_t)u;
}

// 8 f32 -> 8 bf16 via v_cvt_pk_bf16_f32 (no builtin on gfx950; RNE)
__device__ __forceinline__ short8 pack8(f32x4 a, f32x4 b){
  union { short8 s; uint32_t u[4]; } r;
  asm("v_cvt_pk_bf16_f32 %0, %1, %2" : "=v"(r.u[0]) : "v"(a[0]), "v"(a[1]));
  asm("v_cvt_pk_bf16_f32 %0, %1, %2" : "=v"(r.u[1]) : "v"(a[2]), "v"(a[3]));
  asm("v_cvt_pk_bf16_f32 %0, %1, %2" : "=v"(r.u[2]) : "v"(b[0]), "v"(b[1]));
  asm("v_cvt_pk_bf16_f32 %0, %1, %2" : "=v"(r.u[3]) : "v"(b[2]), "v"(b[3]));
  return r.s;
}

#define GLOBAL_AS __attribute__((address_space(1)))
#define LDS_AS    __attribute__((address_space(3)))
__device__ __forceinline__ void async16(const void* g, void* l){
  __builtin_amdgcn_global_load_lds((const GLOBAL_AS uint32_t*)g,
                                   (LDS_AS uint32_t*)l, 16, 0, 0);
}

// ---------------------------------------------------------------------------
// prep = pack_w only. w [E][H] f32 -> wt [3H][E] bf16.  384 blocks.
// ---------------------------------------------------------------------------
__global__ void prep(const float* __restrict__ wq, const float* __restrict__ wk,
                     const float* __restrict__ wv, short* __restrict__ wt){
  __shared__ float t[32][33];
  int idx = blockIdx.x;
  int hb  = idx & 3;
  int eb  = (idx >> 2) & 31;
  int w   = idx >> 7;
  const float* src = (w == 0) ? wq : (w == 1) ? wk : wv;
  int c  = threadIdx.x & 31;
  int r0 = threadIdx.x >> 5;
#pragma unroll
  for (int i = 0; i < 4; i++){
    int r = r0 * 4 + i;
    t[r][c] = src[(size_t)(eb * 32 + r) * H_ + hb * 32 + c];
  }
  __syncthreads();
#pragma unroll
  for (int i = 0; i < 4; i++){
    int r = r0 * 4 + i;
    wt[(size_t)(w * 128 + hb * 32 + r) * E_ + eb * 32 + c] = f2bf(t[c][r]);
  }
}

// ---------------------------------------------------------------------------
// QKV GEMM v9 — 64x128 tile for OCCUPANCY: grid 3x256 = 768 blocks = exactly
// 3 blocks/CU (was 1.5 at 128x128), unlocking cross-block MFMA/VMEM overlap
// (m114 mechanism). Same proven distance-1 fencing + fused f32->bf16
// A-staging as v7; swizzle algebra unchanged (only row&15 / (row>>1)&3 /
// quad enter it). Wave map 2x2 (32m x 64n per wave), acc[2][4].
// LDS: A dbuf 2x4KB [0..4095] | B dbuf 2x8KB [4096..12287]; 24 KB total.
// V-epilogue overlay: [128 h][72] shorts (stride 144 B, 16B-aligned copies).
// ---------------------------------------------------------------------------
__launch_bounds__(256)
__global__ void qkv_gemm(const float* __restrict__ x, const short* __restrict__ wt,
                         short* __restrict__ qm, short* __restrict__ km,
                         short* __restrict__ vt){
  __shared__ __align__(16) short smem[12288];   // 24 KB
  const int wave = threadIdx.x >> 6;
  const int lane = threadIdx.x & 63;
  const int l16  = lane & 15;
  const int quad = lane >> 4;
  const int nb   = blockIdx.x;        // 0..2  (q,k,v)
  const int m0   = blockIdx.y * 64;
  const int n0   = nb * 128;

  f32x4 acc[2][4];
#pragma unroll
  for (int i = 0; i < 2; i++)
#pragma unroll
    for (int j = 0; j < 4; j++) acc[i][j] = (f32x4)(0.0f);

  // A staging: 4 chunks (1/wave), chunk c covers rows c*16..c*16+15,
  // XOR-swizzled 8-col groups; LDS placement c*1024 + lane*16 bytes.
  const int rA = wave * 16 + (lane >> 2);
  const int qA = ((lane & 3) ^ ((rA >> 1) & 3)) & 3;

  f32x4 a0, a1;

#define A_LOAD(k0)                                                            \
  {                                                                           \
    const float* s_ = x + (size_t)(m0 + rA) * E_ + (k0) + qA * 8;             \
    a0 = *(const f32x4*)s_;                                                   \
    a1 = *(const f32x4*)(s_ + 4);                                             \
  }

#define A_WRITE(buf)                                                          \
  {                                                                           \
    *(short8*)((char*)(smem + (buf) * 2048) + wave * 1024 + lane * 16) =      \
        pack8(a0, a1);                                                        \
  }

#define B_STAGE(buf, k0)                                                      \
  {                                                                           \
    _Pragma("unroll")                                                         \
    for (int i = 0; i < 2; i++){                                              \
      int c = wave * 2 + i;                                                   \
      int r = c * 16 + (lane >> 2);                                           \
      int q = ((lane & 3) ^ ((r >> 1) & 3)) & 3;                              \
      async16(wt + (size_t)(n0 + r) * E_ + (k0) + q * 8,                      \
              (char*)(smem + 4096 + (buf) * 4096) + c * 1024);                \
    }                                                                         \
  }

  A_LOAD(0)
  B_STAGE(0, 0)
  A_WRITE(0)
  for (int ks = 0; ks < 32; ks++){
    const int k0 = ks * 32;
    __syncthreads();
    if (ks < 31){
      A_LOAD(k0 + 32)                 // f32 loads in flight across MFMA phase
      B_STAGE((ks + 1) & 1, k0 + 32)
    }

    const short* a = smem + (ks & 1) * 2048;
    const short* b = smem + 4096 + (ks & 1) * 4096;
    short8 af[2], bf[4];
#pragma unroll
    for (int t = 0; t < 2; t++){
      int ra = (wave & 1) * 32 + t * 16 + l16;
      int pa = (quad ^ ((ra >> 1) & 3)) & 3;
      af[t] = *(const short8*)(a + ra * 32 + pa * 8);
    }
#pragma unroll
    for (int t = 0; t < 4; t++){
      int rb = (wave >> 1) * 64 + t * 16 + l16;
      int pb = (quad ^ ((rb >> 1) & 3)) & 3;
      bf[t] = *(const short8*)(b + rb * 32 + pb * 8);
    }
#pragma unroll
    for (int mt = 0; mt < 2; mt++)
#pragma unroll
      for (int nt = 0; nt < 4; nt++)
        acc[mt][nt] = __builtin_amdgcn_mfma_f32_16x16x32_bf16(af[mt], bf[nt], acc[mt][nt], 0, 0, 0);

    if (ks < 31){
      A_WRITE((ks + 1) & 1)           // cvt+ds_write to the buffer read next iter
    }
  }
#undef A_LOAD
#undef A_WRITE
#undef B_STAGE

  if (nb != 2){
    short* dst = (nb == 0) ? qm : km;
#pragma unroll
    for (int mt = 0; mt < 2; mt++)
#pragma unroll
      for (int nt = 0; nt < 4; nt++){
        int row = m0 + (wave & 1) * 32 + mt * 16 + quad * 4;
        int col = (wave >> 1) * 64 + nt * 16 + l16;
#pragma unroll
        for (int r = 0; r < 4; r++)
          dst[(size_t)(row + r) * H_ + col] = f2bf(acc[mt][nt][r]);
      }
  } else {
    __syncthreads();                            // stage bufs dead; reuse as vtile
#pragma unroll
    for (int mt = 0; mt < 2; mt++)
#pragma unroll
      for (int nt = 0; nt < 4; nt++){
        int scol = (wave & 1) * 32 + mt * 16 + quad * 4;   // s within tile (0..63)
        int hrow = (wave >> 1) * 64 + nt * 16 + l16;       // h (0..127)
        short4v t4;
#pragma unroll
        for (int r = 0; r < 4; r++) t4[r] = f2bf(acc[mt][nt][r]);
        *(short4v*)(smem + hrow * 72 + scol) = t4;
      }
    __syncthreads();
    int h   = threadIdx.x >> 1;                 // 0..127
    int s0  = (threadIdx.x & 1) * 32;           // 0 / 32
    int bb_ = m0 >> 11;                         // batch
    short* dstv = vt + ((size_t)bb_ * H_ + h) * S_ + (m0 & (S_ - 1)) + s0;
    const short* srcv = smem + h * 72 + s0;
#pragma unroll
    for (int i = 0; i < 4; i++)
      *(short8*)(dstv + i * 8) = *(const short8*)(srcv + i * 8);
  }
}

// ---------------------------------------------------------------------------
// Attention v6b (UNCHANGED from R4, PASSED): pipelined ISSUE, proven FENCING
// (two __syncthreads/iter, full vmcnt(0)+lgkmcnt(0) drains).
//  - K double-buffered: prefetch for tile it+1 issued BEFORE the QK phase of
//    tile it, drained at the mid __syncthreads.
//  - V staged at iter top, consumed after QK, published by mid __syncthreads.
// LDS 66 KB -> 2 blocks/CU.
// ---------------------------------------------------------------------------
__launch_bounds__(512)
__global__ void attn(const short* __restrict__ qm, const short* __restrict__ km,
                     const short* __restrict__ vtm, const float* __restrict__ du,
                     float* __restrict__ po, float* __restrict__ pl,
                     float* __restrict__ out, int split){
  const int wave = threadIdx.x >> 6;
  const int lane = threadIdx.x & 63;
  const int l16  = lane & 15;
  const int quad = lane >> 4;
  const int sp   = blockIdx.x & (split - 1);    // split is 1/2/4
  const int rbk  = blockIdx.x / split;
  const int b    = rbk >> 4;                    // 16 row-blocks per batch
  const int m0   = (rbk & 15) * 128 + wave * 16;
  const int seg  = S_ / split;

  const short* qb  = qm  + ((size_t)b * S_ + m0) * H_;
  const short* kb  = km  + (size_t)b * S_ * H_;
  const short* vb  = vtm + (size_t)b * H_ * S_;
  const float* dub = du  + ((size_t)b * S_ + m0) * S_;

  __shared__ __align__(16) short kls[2][8192];  // dbuf [64 key][128 k] swizzled
  __shared__ __align__(16) short vls[8192];     // [128 h][64 t]  swizzled
  __shared__ short pbuf[8][16][72];             // bf16 P round-trip, per-wave
  short* pb = &pbuf[wave][0][0];

  short8 qf[4];
#pragma unroll
  for (int kc = 0; kc < 4; kc++)
    qf[kc] = *(const short8*)(qb + (size_t)l16 * H_ + kc * 32 + quad * 8);

  f32x4 o[8];
#pragma unroll
  for (int ht = 0; ht < 8; ht++) o[ht] = (f32x4)(0.0f);
  float lpart[4] = {0.f, 0.f, 0.f, 0.f};

  const float SC2  = 0.045084220f;              // log2(e) / 32
  const float KINV = 1.0f / 0.9f;

#define K_STAGE(bufi, ts)                                                     \
  {                                                                           \
    _Pragma("unroll")                                                         \
    for (int i = 0; i < 2; i++){                                              \
      int c = wave * 2 + i;                                                   \
      int r = c * 4 + (lane >> 4);                                            \
      int s = lane & 15;                                                      \
      int q = (s & 8) | ((s ^ r) & 7);                                        \
      async16(kb + (size_t)((ts) + r) * H_ + q * 8,                           \
              (char*)kls + (bufi) * 16384 + c * 1024);                        \
    }                                                                         \
  }

  const int tbeg = sp * seg;
  const int nIt  = seg >> 6;

  K_STAGE(0, tbeg)                              // prologue: stage tile 0

  for (int it = 0; it < nIt; ++it){
    const int t0  = tbeg + (it << 6);
    const int cur = it & 1;

    __syncthreads();                            // prev PV done -> vls rewritable

    // ---- V stage (current tile) ----
#pragma unroll
    for (int i = 0; i < 2; i++){
      int c = wave * 2 + i;
      int r = c * 8 + (lane >> 3);
      int s = lane & 7;
      int q = (s ^ r) & 7;
      async16(vb + (size_t)r * S_ + t0 + q * 8, (char*)vls + c * 1024);
    }

    // ---- du loads (unique data), consumed after QK ----
    const float* dp = dub + (size_t)l16 * S_ + t0 + quad * 8;
    f32x4 u0 = *(const f32x4*)(dp);
    f32x4 u1 = *(const f32x4*)(dp + 4);
    f32x4 u2 = *(const f32x4*)(dp + 32);
    f32x4 u3 = *(const f32x4*)(dp + 36);

    // ---- K prefetch (next tile; wraps harmlessly on last iter) ----
    const int nt0 = (it + 1 < nIt) ? (t0 + 64) : tbeg;
    K_STAGE(cur ^ 1, nt0)

    // ---- S = Q K^T  (reads kls[cur], staged last iter, drained at mid sync)
    f32x4 s[4];
#pragma unroll
    for (int nt = 0; nt < 4; nt++) s[nt] = (f32x4)(0.0f);
#pragma unroll
    for (int nt = 0; nt < 4; nt++){
      int row = nt * 16 + l16;
#pragma unroll
      for (int kc = 0; kc < 4; kc++){
        int q  = kc * 4 + quad;
        int ph = (q & 8) | ((q ^ row) & 7);
        short8 bf = *(const short8*)((const char*)kls + cur * 16384 + row * 256 + ph * 16);
        s[nt] = __builtin_amdgcn_mfma_f32_16x16x32_bf16(qf[kc], bf, s[nt], 0, 0, 0);
      }
    }

    // ---- p = exp2(s*SC2); per-lane l; stage bf16 P to pbuf (C-layout) ----
#pragma unroll
    for (int nt = 0; nt < 4; nt++)
#pragma unroll
      for (int r = 0; r < 4; r++){
        float p = exp2f(s[nt][r] * SC2);
        lpart[r] += p;
        pb[(quad * 4 + r) * 72 + nt * 16 + l16] = f2bf(p);
      }

    __builtin_amdgcn_sched_barrier(0);
    __builtin_amdgcn_s_waitcnt(0xC07F);         // lgkmcnt(0) only
    __builtin_amdgcn_sched_barrier(0);

    // ---- A-layout read + dropout select (scale folded to epilogue) ----
    const short* pr = pb + l16 * 72 + quad * 8;
    short8 pb0 = *(const short8*)(pr);
    short8 pb1 = *(const short8*)(pr + 32);
    short8 pa0, pa1;
#pragma unroll
    for (int j = 0; j < 4; j++){
      pa0[j]     = (u0[j] >= 0.1f) ? pb0[j]     : (short)0;
      pa0[j + 4] = (u1[j] >= 0.1f) ? pb0[j + 4] : (short)0;
      pa1[j]     = (u2[j] >= 0.1f) ? pb1[j]     : (short)0;
      pa1[j + 4] = (u3[j] >= 0.1f) ? pb1[j + 4] : (short)0;
    }

    __syncthreads();                            // mid: publish V (full drain)

    // ---- O += P V ----
#pragma unroll
    for (int ht = 0; ht < 8; ht++){
      int row = ht * 16 + l16;
#pragma unroll
      for (int half = 0; half < 2; half++){
        int q  = half * 4 + quad;
        int ph = (q ^ row) & 7;
        short8 vf = *(const short8*)((const char*)vls + row * 128 + ph * 16);
        o[ht] = __builtin_amdgcn_mfma_f32_16x16x32_bf16(half ? pa1 : pa0, vf, o[ht], 0, 0, 0);
      }
    }
  }
#undef K_STAGE

  float lrow[4];
#pragma unroll
  for (int r = 0; r < 4; r++){
    float v = lpart[r];
    v += __shfl_xor(v, 1);
    v += __shfl_xor(v, 2);
    v += __shfl_xor(v, 4);
    v += __shfl_xor(v, 8);
    lrow[r] = v;
  }

  if (split == 1){
    float* op = out + ((size_t)b * S_ + m0) * H_;
#pragma unroll
    for (int ht = 0; ht < 8; ht++)
#pragma unroll
      for (int r = 0; r < 4; r++)
        op[(size_t)(quad * 4 + r) * H_ + ht * 16 + l16] = o[ht][r] * KINV / lrow[r];
  } else {
#pragma unroll
    for (int r = 0; r < 4; r++){
      size_t R = (size_t)b * S_ + m0 + quad * 4 + r;
#pragma unroll
      for (int ht = 0; ht < 8; ht++)
        po[((size_t)sp * NR_ + R) * H_ + ht * 16 + l16] = o[ht][r] * KINV;
      if (l16 == 0) pl[(size_t)sp * NR_ + R] = lrow[r];
    }
  }
}

// ---------------------------------------------------------------------------
__global__ void combine(const float* __restrict__ po, const float* __restrict__ pl,
                        float* __restrict__ out, int split){
  int row = blockIdx.x;
  int col = threadIdx.x;
  float num = 0.f, den = 0.f;
  for (int s = 0; s < split; s++){
    num += po[((size_t)s * NR_ + row) * H_ + col];
    den += pl[(size_t)s * NR_ + row];
  }
  out[(size_t)row * H_ + col] = num / den;
}

// ---------------------------------------------------------------------------
extern "C" void kernel_launch(void* const* d_in, const int* in_sizes, int n_in,
                              void* d_out, int out_size, void* d_ws, size_t ws_size,
                              hipStream_t stream){
  const float* x  = (const float*)d_in[0];
  const float* wq = (const float*)d_in[1];
  const float* wk = (const float*)d_in[2];
  const float* wv = (const float*)d_in[3];
  const float* du = (const float*)d_in[4];
  float* out = (float*)d_out;

  const size_t MiB = 1048576;
  char* ws = (char*)d_ws;
  short* qm = (short*)(ws);                      // 4 MiB
  short* km = (short*)(ws + 4 * MiB);            // 4 MiB
  short* vt = (short*)(ws + 8 * MiB);            // 4 MiB
  short* wt = (short*)(ws + 44 * MiB);           // 768 KiB
  float* pl = (float*)(ws + 45 * MiB);           // split*64 KiB
  float* po = (float*)(ws + 45 * MiB + 524288);  // split*8 MiB

  size_t base  = 45 * MiB + 524288;
  size_t needA = base + 32 * MiB;
  size_t needB = base + 16 * MiB;
  int split = (ws_size >= needA) ? 4 : (ws_size >= needB) ? 2 : 1;

  hipLaunchKernelGGL(prep,     dim3(384),         dim3(256), 0, stream, wq, wk, wv, wt);
  hipLaunchKernelGGL(qkv_gemm, dim3(3, 256),      dim3(256), 0, stream, x, wt, qm, km, vt);
  hipLaunchKernelGGL(attn,     dim3(128 * split), dim3(512), 0, stream,
                     qm, km, vt, du, po, pl, out, split);
  if (split > 1)
    hipLaunchKernelGGL(combine, dim3(NR_), dim3(H_), 0, stream, po, pl, out, split);
}